// Round 1
// 195.509 us; speedup vs baseline: 1.0142x; 1.0142x over previous
//
#include <hip/hip_runtime.h>

// LJ constants (sigma=1, eps=1, cutoff=5)
// SHIFT = 4*((1/5)^12 - (1/5)^6)
__device__ __constant__ float kShift = 4.0f * (float)(1.0 / 244140625.0 - 1.0 / 15625.0);

#define GROUPS 3
#define MAX_MEMBERS 85             // 3*85 = 255 blocks, 1 per CU
#define BUCKET 33334               // atoms per group; 133,336 B LDS
#define BLOCK_T 1024               // 16 waves
#define RED_SPLIT 4                // member-axis split in reduce

// Structural model (R3-R7, confirmed by this session's counters): the LDS
// atomic unit processes scattered ds_add_f32 at ~4 cyc per ACTIVE lane-add
// per CU (fits 3.9-4.2 across five configs spanning 3x fetch-traffic —
// i.e. active-fraction variation — and ILP variation; per-active-lane cost,
// not per-instruction). 12.8M adds / 255 CUs * ~4 cyc => ~82 us floor;
// measured 79.6-80.1. Compaction/multi-block-per-CU cannot beat it; global
// atomic offload measured -45% (R6/R7). Gather is left untouched at the
// floor configuration. This round parallelizes the reduce 4x to rule out
// a latency-bound second kernel as the source of the dur_us - 80us gap.

__device__ __forceinline__ float lj_half_e(float x, float y, float z) {
    float r2 = x * x + y * y + z * z;
    float inv_r2 = __builtin_amdgcn_rcpf(r2);   // ~1e-5 rel err, tol is huge
    float sr6 = inv_r2 * inv_r2 * inv_r2;       // (sigma/r)^6
    float sr12 = sr6 * sr6;
    // 0.5 * (4*(sr12-sr6) - shift) = 2*(sr12-sr6) - 0.5*shift
    return __builtin_fmaf(sr12 - sr6, 2.0f, -0.5f * kShift);
}

__global__ __launch_bounds__(BLOCK_T) void lj_gather_group(
        const float* __restrict__ dist,
        const int* __restrict__ atom_a,
        const int* __restrict__ atom_b,
        float* __restrict__ ws,
        int members, int n_edges) {
    __shared__ float acc[BUCKET];

    const int g = blockIdx.x / members;     // atom-range owner
    const int m = blockIdx.x % members;     // edge slice
    const unsigned lo = (unsigned)(g * BUCKET);

    for (int i = threadIdx.x; i < BUCKET; i += BLOCK_T) acc[i] = 0.0f;
    __syncthreads();

    const long long quads = (long long)n_edges >> 2;
    const long long per = (quads + members - 1) / members;
    const long long q0 = (long long)m * per;
    const long long qe = (q0 + per < quads) ? (q0 + per) : quads;

    for (long long q = q0 + threadIdx.x; q < qe; q += BLOCK_T) {
        const float4* d4 = (const float4*)(dist) + (size_t)q * 3;
        float4 v0 = d4[0];
        float4 v1 = d4[1];
        float4 v2 = d4[2];
        int4 ia = ((const int4*)atom_a)[q];
        int4 ib = ((const int4*)atom_b)[q];

        float h0 = lj_half_e(v0.x, v0.y, v0.z);
        float h1 = lj_half_e(v0.w, v1.x, v1.y);
        float h2 = lj_half_e(v1.z, v1.w, v2.x);
        float h3 = lj_half_e(v2.y, v2.z, v2.w);

        unsigned u;
        u = (unsigned)ia.x - lo; if (u < BUCKET) atomicAdd(&acc[u], h0);
        u = (unsigned)ib.x - lo; if (u < BUCKET) atomicAdd(&acc[u], h0);
        u = (unsigned)ia.y - lo; if (u < BUCKET) atomicAdd(&acc[u], h1);
        u = (unsigned)ib.y - lo; if (u < BUCKET) atomicAdd(&acc[u], h1);
        u = (unsigned)ia.z - lo; if (u < BUCKET) atomicAdd(&acc[u], h2);
        u = (unsigned)ib.z - lo; if (u < BUCKET) atomicAdd(&acc[u], h2);
        u = (unsigned)ia.w - lo; if (u < BUCKET) atomicAdd(&acc[u], h3);
        u = (unsigned)ib.w - lo; if (u < BUCKET) atomicAdd(&acc[u], h3);
    }

    // Edge-count tail (n_edges % 4 != 0): last slice handles it.
    if ((n_edges & 3) && m == members - 1) {
        for (long long e = quads * 4 + threadIdx.x; e < n_edges; e += BLOCK_T) {
            float x = dist[e * 3 + 0];
            float y = dist[e * 3 + 1];
            float z = dist[e * 3 + 2];
            float h = lj_half_e(x, y, z);
            unsigned u;
            u = (unsigned)atom_a[e] - lo; if (u < BUCKET) atomicAdd(&acc[u], h);
            u = (unsigned)atom_b[e] - lo; if (u < BUCKET) atomicAdd(&acc[u], h);
        }
    }
    __syncthreads();

    float* dst = ws + (size_t)(g * members + m) * BUCKET;
    for (int i = threadIdx.x; i < BUCKET; i += BLOCK_T) dst[i] = acc[i];
}

// out[a] = sum over the `members` partials of a's group.
// 4 threads per atom (member-axis split), quad butterfly combine.
// 1563 blocks * 4 waves ~= 24 waves/CU: kills latency-bound risk of the
// previous 391-block / 85-deep-chain version.
__global__ __launch_bounds__(256) void reduce_groups(const float* __restrict__ ws,
                              float* __restrict__ out,
                              int members, int n_atoms) {
    int t = blockIdx.x * blockDim.x + threadIdx.x;
    int ai = t >> 2;                 // atom index
    int s = t & 3;                   // member-axis sub-lane
    int i = (ai < n_atoms) ? ai : (n_atoms - 1);  // clamp: keep quad alive for shfl
    int g = i / BUCKET;
    int off = i - g * BUCKET;
    const float* base = ws + ((size_t)g * members) * BUCKET + off;
    float sum = 0.0f;
    #pragma unroll 8
    for (int b = s; b < members; b += RED_SPLIT) sum += base[(size_t)b * BUCKET];
    sum += __shfl_xor(sum, 1);
    sum += __shfl_xor(sum, 2);
    if (s == 0 && ai < n_atoms) out[ai] = sum;
}

// Fallback (ws far too small): device-scope atomics straight into out. Slow but correct.
__global__ void lj_scatter_direct(const float* __restrict__ dist,
                                  const int* __restrict__ atom_a,
                                  const int* __restrict__ atom_b,
                                  float* __restrict__ out,
                                  int n_edges) {
    int t = blockIdx.x * blockDim.x + threadIdx.x;
    long long e0 = (long long)t * 4;
    if (e0 >= n_edges) return;
    if (e0 + 3 < n_edges) {
        const float4* d4 = (const float4*)(dist) + (size_t)t * 3;
        float4 v0 = d4[0];
        float4 v1 = d4[1];
        float4 v2 = d4[2];
        int4 ia = ((const int4*)atom_a)[t];
        int4 ib = ((const int4*)atom_b)[t];
        float h0 = lj_half_e(v0.x, v0.y, v0.z);
        float h1 = lj_half_e(v0.w, v1.x, v1.y);
        float h2 = lj_half_e(v1.z, v1.w, v2.x);
        float h3 = lj_half_e(v2.y, v2.z, v2.w);
        atomicAdd(&out[ia.x], h0);
        atomicAdd(&out[ib.x], h0);
        atomicAdd(&out[ia.y], h1);
        atomicAdd(&out[ib.y], h1);
        atomicAdd(&out[ia.z], h2);
        atomicAdd(&out[ib.z], h2);
        atomicAdd(&out[ia.w], h3);
        atomicAdd(&out[ib.w], h3);
    } else {
        for (long long e = e0; e < n_edges; ++e) {
            float x = dist[e * 3 + 0];
            float y = dist[e * 3 + 1];
            float z = dist[e * 3 + 2];
            float h = lj_half_e(x, y, z);
            atomicAdd(&out[atom_a[e]], h);
            atomicAdd(&out[atom_b[e]], h);
        }
    }
}

extern "C" void kernel_launch(void* const* d_in, const int* in_sizes, int n_in,
                              void* d_out, int out_size, void* d_ws, size_t ws_size,
                              hipStream_t stream) {
    const float* dist = (const float*)d_in[0];
    const int* atom_a = (const int*)d_in[1];
    const int* atom_b = (const int*)d_in[2];
    float* out = (float*)d_out;

    int n_edges = in_sizes[1];
    int n_atoms = out_size;

    size_t per_member = (size_t)GROUPS * BUCKET * sizeof(float);
    int members = (int)(ws_size / per_member);
    if (members > MAX_MEMBERS) members = MAX_MEMBERS;
    bool range_ok = ((long long)GROUPS * BUCKET >= (long long)n_atoms);

    if (members >= 8 && range_ok) {
        float* ws = (float*)d_ws;
        lj_gather_group<<<GROUPS * members, BLOCK_T, 0, stream>>>(
            dist, atom_a, atom_b, ws, members, n_edges);
        int rblock = 256;
        long long rthreads = (long long)n_atoms * RED_SPLIT;
        int rgrid = (int)((rthreads + rblock - 1) / rblock);
        reduce_groups<<<rgrid, rblock, 0, stream>>>(ws, out, members, n_atoms);
    } else {
        hipMemsetAsync(d_out, 0, (size_t)n_atoms * sizeof(float), stream);
        int n_quads = (n_edges + 3) / 4;
        int block = 256;
        int grid = (n_quads + block - 1) / block;
        lj_scatter_direct<<<grid, block, 0, stream>>>(dist, atom_a, atom_b, out, n_edges);
    }
}